// Round 5
// baseline (250.347 us; speedup 1.0000x reference)
//
#include <hip/hip_runtime.h>
#include <hip/hip_cooperative_groups.h>
#include <math.h>

namespace cg = cooperative_groups;

#define VOXEL 32
#define NCELL (VOXEL * VOXEL)  // 1024 cells per batch
#define CAP 64                 // bucket capacity; Poisson(8) => P(>=64) ~ 1e-38
#define OVF_MAX 4096
#define COOP_BLOCKS 256
#define COOP_THREADS 1024

// ---------- helpers ----------

__device__ __forceinline__ int cell_of(const float* __restrict__ coords, int point, int N) {
    float x = coords[(size_t)point * 2 + 0];
    float y = coords[(size_t)point * 2 + 1];
    int gx = (int)(x * (float)(VOXEL - 1));  // trunc == astype(int32) for x>=0
    int gy = (int)(y * (float)(VOXEL - 1));
    gx = min(max(gx, 0), VOXEL - 1);
    gy = min(max(gy, 0), VOXEL - 1);
    int b = point / N;
    return b * NCELL + gy * VOXEL + gx;
}

__device__ __forceinline__ void fmax4(float4& m, const float4 v) {
    m.x = fmaxf(m.x, v.x); m.y = fmaxf(m.y, v.y);
    m.z = fmaxf(m.z, v.z); m.w = fmaxf(m.w, v.w);
}

// ---------- single cooperative kernel: zero -> scatter -> gather -> cleanup ----------

__global__ void __launch_bounds__(COOP_THREADS)
voxelize_coop(const float* __restrict__ feat, const float* __restrict__ coords,
              unsigned int* __restrict__ counts,    // [totc]
              unsigned int* __restrict__ ovf_cnt,   // [16] (contiguous after counts)
              unsigned int* __restrict__ ovf_list,  // [OVF_MAX]
              unsigned int* __restrict__ sorted,    // [totc*CAP]
              float* __restrict__ out,
              int BN, int N, int F, int totc) {
    cg::grid_group grid = cg::this_grid();
    const int gtid = blockIdx.x * COOP_THREADS + threadIdx.x;
    const int nthreads = gridDim.x * COOP_THREADS;

    // Phase A: zero counts + ovf_cnt (contiguous in ws)
    for (int i = gtid; i < totc + 16; i += nthreads) counts[i] = 0u;
    __threadfence();
    grid.sync();

    // Phase B: scatter point ids into fixed-capacity buckets
    for (int p = gtid; p < BN; p += nthreads) {
        int c = cell_of(coords, p, N);
        unsigned int pos = atomicAdd(&counts[c], 1u);
        if (pos < CAP) {
            sorted[(size_t)c * CAP + pos] = (unsigned int)p;
        } else {
            unsigned int o = atomicAdd(ovf_cnt, 1u);
            if (o < OVF_MAX) ovf_list[o] = (unsigned int)p;
        }
    }
    __threadfence();
    grid.sync();

    // Phase C: gather-max. One wave per cell, strided; lane owns feats [4*lane,4*lane+4).
    const int lane  = threadIdx.x & 63;
    const int gwave = gtid >> 6;
    const int nwaves = nthreads >> 6;
    for (int cell = gwave; cell < totc; cell += nwaves) {
        unsigned int cnt = counts[cell];
        if (cnt > CAP) cnt = CAP;
        const size_t cb = (size_t)cell * CAP;
        unsigned int pid_l = (lane < (int)cnt) ? sorted[cb + lane] : 0u;

        float4 m = make_float4(-INFINITY, -INFINITY, -INFINITY, -INFINITY);
        int j = 0;
        // 4-wide unroll: 4 independent 1KB row-loads in flight per step
        for (; j + 4 <= (int)cnt; j += 4) {
            const int p0 = __shfl((int)pid_l, j + 0);
            const int p1 = __shfl((int)pid_l, j + 1);
            const int p2 = __shfl((int)pid_l, j + 2);
            const int p3 = __shfl((int)pid_l, j + 3);
            const float4 v0 = *(const float4*)(feat + (size_t)p0 * F + lane * 4);
            const float4 v1 = *(const float4*)(feat + (size_t)p1 * F + lane * 4);
            const float4 v2 = *(const float4*)(feat + (size_t)p2 * F + lane * 4);
            const float4 v3 = *(const float4*)(feat + (size_t)p3 * F + lane * 4);
            fmax4(m, v0); fmax4(m, v1); fmax4(m, v2); fmax4(m, v3);
        }
        for (; j < (int)cnt; ++j) {
            const int p0 = __shfl((int)pid_l, j);
            const float4 v0 = *(const float4*)(feat + (size_t)p0 * F + lane * 4);
            fmax4(m, v0);
        }
        if (cnt == 0) m = make_float4(0.f, 0.f, 0.f, 0.f);
        *(float4*)(out + (size_t)cell * F + lane * 4) = m;
    }

    // Phase D: overflow cleanup (never taken for sane inputs; kept for correctness)
    unsigned int novf = *(volatile unsigned int*)ovf_cnt;
    if (novf > 0) {
        __threadfence();
        grid.sync();
        if (blockIdx.x == 0) {
            unsigned int n = min(novf, (unsigned int)OVF_MAX);
            const int wave = threadIdx.x >> 6;
            for (unsigned int i = wave; i < n; i += COOP_THREADS / 64) {
                unsigned int p = ovf_list[i];
                int c = cell_of(coords, p, N);
#pragma unroll
                for (int k = 0; k < 4; ++k) {
                    float v = feat[(size_t)p * F + lane * 4 + k];
                    unsigned int* addr = (unsigned int*)&out[(size_t)c * F + lane * 4 + k];
                    float old = __uint_as_float(*addr);
                    while (v > old) {
                        unsigned int assumed = __float_as_uint(old);
                        unsigned int prev = atomicCAS(addr, assumed, __float_as_uint(v));
                        if (prev == assumed) break;
                        old = __uint_as_float(prev);
                    }
                }
            }
        }
    }
}

// ---------- non-cooperative fallback (round-3 structure) ----------

__global__ void zero_kernel(unsigned int* __restrict__ p, int n) {
    int i = blockIdx.x * blockDim.x + threadIdx.x;
    if (i < n) p[i] = 0u;
}

__global__ void scatter_bucket(const float* __restrict__ coords,
                               unsigned int* __restrict__ counts,
                               unsigned int* __restrict__ sorted,
                               unsigned int* __restrict__ ovf_cnt,
                               unsigned int* __restrict__ ovf_list,
                               int BN, int N) {
    int p = blockIdx.x * blockDim.x + threadIdx.x;
    if (p >= BN) return;
    int c = cell_of(coords, p, N);
    unsigned int pos = atomicAdd(&counts[c], 1u);
    if (pos < CAP) sorted[(size_t)c * CAP + pos] = (unsigned int)p;
    else {
        unsigned int o = atomicAdd(ovf_cnt, 1u);
        if (o < OVF_MAX) ovf_list[o] = (unsigned int)p;
    }
}

__global__ void gather_kernel(const float* __restrict__ feat,
                              const unsigned int* __restrict__ sorted,
                              const unsigned int* __restrict__ counts,
                              float* __restrict__ out, int F) {
    const int wave = threadIdx.x >> 6;
    const int lane = threadIdx.x & 63;
    const int cell = blockIdx.x * 4 + wave;

    unsigned int cnt = counts[cell];
    if (cnt > CAP) cnt = CAP;
    const size_t cb = (size_t)cell * CAP;
    unsigned int pid_l = (lane < (int)cnt) ? sorted[cb + lane] : 0u;

    float4 m = make_float4(-INFINITY, -INFINITY, -INFINITY, -INFINITY);
    int j = 0;
    for (; j + 4 <= (int)cnt; j += 4) {
        const int p0 = __shfl((int)pid_l, j + 0);
        const int p1 = __shfl((int)pid_l, j + 1);
        const int p2 = __shfl((int)pid_l, j + 2);
        const int p3 = __shfl((int)pid_l, j + 3);
        const float4 v0 = *(const float4*)(feat + (size_t)p0 * F + lane * 4);
        const float4 v1 = *(const float4*)(feat + (size_t)p1 * F + lane * 4);
        const float4 v2 = *(const float4*)(feat + (size_t)p2 * F + lane * 4);
        const float4 v3 = *(const float4*)(feat + (size_t)p3 * F + lane * 4);
        fmax4(m, v0); fmax4(m, v1); fmax4(m, v2); fmax4(m, v3);
    }
    for (; j < (int)cnt; ++j) {
        const int p0 = __shfl((int)pid_l, j);
        const float4 v0 = *(const float4*)(feat + (size_t)p0 * F + lane * 4);
        fmax4(m, v0);
    }
    if (cnt == 0) m = make_float4(0.f, 0.f, 0.f, 0.f);
    *(float4*)(out + (size_t)cell * F + lane * 4) = m;
}

__global__ void cleanup_kernel(const float* __restrict__ feat,
                               const float* __restrict__ coords,
                               const unsigned int* __restrict__ ovf_cnt,
                               const unsigned int* __restrict__ ovf_list,
                               float* __restrict__ out, int N, int F) {
    unsigned int n = min(*ovf_cnt, (unsigned int)OVF_MAX);
    if (n == 0) return;
    const int wave = threadIdx.x >> 6;
    const int lane = threadIdx.x & 63;
    for (unsigned int i = wave; i < n; i += 4) {
        unsigned int p = ovf_list[i];
        int c = cell_of(coords, p, N);
#pragma unroll
        for (int k = 0; k < 4; ++k) {
            float v = feat[(size_t)p * F + lane * 4 + k];
            unsigned int* addr = (unsigned int*)&out[(size_t)c * F + lane * 4 + k];
            float old = __uint_as_float(*addr);
            while (v > old) {
                unsigned int assumed = __float_as_uint(old);
                unsigned int prev = atomicCAS(addr, assumed, __float_as_uint(v));
                if (prev == assumed) break;
                old = __uint_as_float(prev);
            }
        }
    }
}

// ---------- last-resort fallback (round-1 atomic path, any F%4==0) ----------

__device__ __forceinline__ unsigned int enc_f32(float f) {
    unsigned int u = __float_as_uint(f);
    return (u & 0x80000000u) ? ~u : (u | 0x80000000u);
}
__device__ __forceinline__ float dec_f32(unsigned int u) {
    if (u == 0u) return 0.0f;
    return __uint_as_float((u & 0x80000000u) ? (u ^ 0x80000000u) : ~u);
}

__global__ void voxel_scatter_max(const float* __restrict__ feat,
                                  const float* __restrict__ coords,
                                  unsigned int* __restrict__ out,
                                  int BN, int N, int F) {
    int gid   = blockIdx.x * blockDim.x + threadIdx.x;
    int point = gid / (F / 4);
    int fi    = gid % (F / 4);
    if (point >= BN) return;
    int idx = cell_of(coords, point, N);
    const float4 v = *(const float4*)(feat + (size_t)point * F + fi * 4);
    unsigned int* o = out + (size_t)idx * F + fi * 4;
    atomicMax(o + 0, enc_f32(v.x));
    atomicMax(o + 1, enc_f32(v.y));
    atomicMax(o + 2, enc_f32(v.z));
    atomicMax(o + 3, enc_f32(v.w));
}

__global__ void voxel_decode(unsigned int* __restrict__ out, int n4) {
    int i = blockIdx.x * blockDim.x + threadIdx.x;
    if (i >= n4) return;
    uint4 u = ((const uint4*)out)[i];
    float4 f;
    f.x = dec_f32(u.x); f.y = dec_f32(u.y);
    f.z = dec_f32(u.z); f.w = dec_f32(u.w);
    ((float4*)out)[i] = f;
}

// ---------- launch ----------

extern "C" void kernel_launch(void* const* d_in, const int* in_sizes, int n_in,
                              void* d_out, int out_size, void* d_ws, size_t ws_size,
                              hipStream_t stream) {
    const float* feat   = (const float*)d_in[0];
    const float* coords = (const float*)d_in[1];
    float* out          = (float*)d_out;

    const int BN = in_sizes[1] / 2;             // 131072 points
    const int F  = in_sizes[0] / BN;            // 256
    const int B  = out_size / (NCELL * F);      // 16
    const int N  = BN / B;                      // 8192
    const int totc = B * NCELL;                 // 16384

    // ws layout (uint): counts[totc] | ovf_cnt[16] | ovf_list[OVF_MAX] | sorted[totc*CAP]
    const size_t ws_need = ((size_t)totc + 16 + OVF_MAX + (size_t)totc * CAP) * 4;
    const bool fast_ok = (F == 256) && (B * N == BN) && (B * NCELL * F == out_size) &&
                         (ws_size >= ws_need);

    if (fast_ok) {
        unsigned int* counts   = (unsigned int*)d_ws;
        unsigned int* ovf_cnt  = counts + totc;
        unsigned int* ovf_list = ovf_cnt + 16;
        unsigned int* sorted   = ovf_list + OVF_MAX;

        int BN_ = BN, N_ = N, F_ = F, totc_ = totc;
        void* args[] = {(void*)&feat, (void*)&coords, (void*)&counts, (void*)&ovf_cnt,
                        (void*)&ovf_list, (void*)&sorted, (void*)&out,
                        (void*)&BN_, (void*)&N_, (void*)&F_, (void*)&totc_};
        hipError_t err = hipLaunchCooperativeKernel((void*)voxelize_coop,
                                                    dim3(COOP_BLOCKS), dim3(COOP_THREADS),
                                                    args, 0, stream);
        if (err == hipSuccess) return;

        // cooperative launch unavailable -> 4-dispatch fallback
        zero_kernel<<<(totc + 16 + 255) / 256, 256, 0, stream>>>(counts, totc + 16);
        scatter_bucket<<<(BN + 255) / 256, 256, 0, stream>>>(coords, counts, sorted,
                                                             ovf_cnt, ovf_list, BN, N);
        gather_kernel<<<totc / 4, 256, 0, stream>>>(feat, sorted, counts, out, F);
        cleanup_kernel<<<1, 256, 0, stream>>>(feat, coords, ovf_cnt, ovf_list, out, N, F);
    } else {
        hipMemsetAsync(d_out, 0, (size_t)out_size * sizeof(float), stream);
        int threads = BN * (F / 4);
        voxel_scatter_max<<<(threads + 255) / 256, 256, 0, stream>>>(feat, coords,
                                                                     (unsigned int*)d_out,
                                                                     BN, N, F);
        int n4 = out_size / 4;
        voxel_decode<<<(n4 + 255) / 256, 256, 0, stream>>>((unsigned int*)d_out, n4);
    }
}

// Round 6
// 39.530 us; speedup vs baseline: 6.3331x; 6.3331x over previous
//
#include <hip/hip_runtime.h>
#include <math.h>

#define VOXEL 32
#define NCELL (VOXEL * VOXEL)  // 1024 cells per batch
#define CAP 64                 // bucket capacity; Poisson(8) => P(>=64) ~ 1e-38
#define OVF_MAX 4096

// ---------- helpers ----------

__device__ __forceinline__ int cell_of(const float* __restrict__ coords, int point, int N) {
    float x = coords[(size_t)point * 2 + 0];
    float y = coords[(size_t)point * 2 + 1];
    int gx = (int)(x * (float)(VOXEL - 1));  // trunc == astype(int32) for x>=0
    int gy = (int)(y * (float)(VOXEL - 1));
    gx = min(max(gx, 0), VOXEL - 1);
    gy = min(max(gy, 0), VOXEL - 1);
    int b = point / N;
    return b * NCELL + gy * VOXEL + gx;
}

__device__ __forceinline__ void fmax4(float4& m, const float4 v) {
    m.x = fmaxf(m.x, v.x); m.y = fmaxf(m.y, v.y);
    m.z = fmaxf(m.z, v.z); m.w = fmaxf(m.w, v.w);
}

// ---------- 3-dispatch binned path ----------

__global__ void zero_kernel(unsigned int* __restrict__ p, int n) {
    int i = blockIdx.x * blockDim.x + threadIdx.x;
    if (i < n) p[i] = 0u;
}

__global__ void scatter_bucket(const float* __restrict__ coords,
                               unsigned int* __restrict__ counts,
                               unsigned int* __restrict__ sorted,
                               unsigned int* __restrict__ ovf_cnt,
                               unsigned int* __restrict__ ovf_list,
                               int BN, int N) {
    int p = blockIdx.x * blockDim.x + threadIdx.x;
    if (p >= BN) return;
    const float2 xy = ((const float2*)coords)[p];
    int gx = (int)(xy.x * (float)(VOXEL - 1));
    int gy = (int)(xy.y * (float)(VOXEL - 1));
    gx = min(max(gx, 0), VOXEL - 1);
    gy = min(max(gy, 0), VOXEL - 1);
    int c = (p / N) * NCELL + gy * VOXEL + gx;
    unsigned int pos = atomicAdd(&counts[c], 1u);
    if (pos < CAP) {
        sorted[(size_t)c * CAP + pos] = (unsigned int)p;
    } else {
        unsigned int o = atomicAdd(ovf_cnt, 1u);
        if (o < OVF_MAX) ovf_list[o] = (unsigned int)p;
    }
}

// One wave per cell (4 waves / 256-thread block). Lane owns feats [4*lane, 4*lane+4).
// 8-wide batches with clamped index: all 8 row-loads independent; padded slots
// re-read the last row (L1 hit), so MLP without extra HBM traffic.
// Overflow points are folded in here (cold path, ovf_cnt==0 in practice).
__global__ void __launch_bounds__(256)
gather_kernel(const float* __restrict__ feat,
              const float* __restrict__ coords,
              const unsigned int* __restrict__ sorted,
              const unsigned int* __restrict__ counts,
              const unsigned int* __restrict__ ovf_cnt,
              const unsigned int* __restrict__ ovf_list,
              float* __restrict__ out, int N, int F) {
    const int wave = threadIdx.x >> 6;
    const int lane = threadIdx.x & 63;
    const int cell = blockIdx.x * 4 + wave;

    const unsigned int raw = counts[cell];
    const int cnt = (int)min(raw, (unsigned int)CAP);
    const size_t cb = (size_t)cell * CAP;
    unsigned int pid_l = (lane < cnt) ? sorted[cb + lane] : 0u;

    float4 m = make_float4(-INFINITY, -INFINITY, -INFINITY, -INFINITY);
    const int e = cnt - 1;
    for (int j = 0; j < cnt; j += 8) {
        const int p0 = __shfl((int)pid_l, min(j + 0, e));
        const int p1 = __shfl((int)pid_l, min(j + 1, e));
        const int p2 = __shfl((int)pid_l, min(j + 2, e));
        const int p3 = __shfl((int)pid_l, min(j + 3, e));
        const int p4 = __shfl((int)pid_l, min(j + 4, e));
        const int p5 = __shfl((int)pid_l, min(j + 5, e));
        const int p6 = __shfl((int)pid_l, min(j + 6, e));
        const int p7 = __shfl((int)pid_l, min(j + 7, e));
        const float4 v0 = *(const float4*)(feat + (size_t)p0 * F + lane * 4);
        const float4 v1 = *(const float4*)(feat + (size_t)p1 * F + lane * 4);
        const float4 v2 = *(const float4*)(feat + (size_t)p2 * F + lane * 4);
        const float4 v3 = *(const float4*)(feat + (size_t)p3 * F + lane * 4);
        const float4 v4 = *(const float4*)(feat + (size_t)p4 * F + lane * 4);
        const float4 v5 = *(const float4*)(feat + (size_t)p5 * F + lane * 4);
        const float4 v6 = *(const float4*)(feat + (size_t)p6 * F + lane * 4);
        const float4 v7 = *(const float4*)(feat + (size_t)p7 * F + lane * 4);
        fmax4(m, v0); fmax4(m, v1); fmax4(m, v2); fmax4(m, v3);
        fmax4(m, v4); fmax4(m, v5); fmax4(m, v6); fmax4(m, v7);
    }

    // Cold path: points that spilled past CAP anywhere in the grid.
    const unsigned int novf = *ovf_cnt;
    if (novf != 0u) {
        const int n = (int)min(novf, (unsigned int)OVF_MAX);
        for (int i = 0; i < n; ++i) {
            const unsigned int p = ovf_list[i];
            if (cell_of(coords, (int)p, N) == cell) {
                const float4 v = *(const float4*)(feat + (size_t)p * F + lane * 4);
                fmax4(m, v);
            }
        }
    }

    if (raw == 0u) m = make_float4(0.f, 0.f, 0.f, 0.f);
    *(float4*)(out + (size_t)cell * F + lane * 4) = m;
}

// ---------- last-resort fallback (round-1 atomic path, any F%4==0) ----------

__device__ __forceinline__ unsigned int enc_f32(float f) {
    unsigned int u = __float_as_uint(f);
    return (u & 0x80000000u) ? ~u : (u | 0x80000000u);
}
__device__ __forceinline__ float dec_f32(unsigned int u) {
    if (u == 0u) return 0.0f;
    return __uint_as_float((u & 0x80000000u) ? (u ^ 0x80000000u) : ~u);
}

__global__ void voxel_scatter_max(const float* __restrict__ feat,
                                  const float* __restrict__ coords,
                                  unsigned int* __restrict__ out,
                                  int BN, int N, int F) {
    int gid   = blockIdx.x * blockDim.x + threadIdx.x;
    int point = gid / (F / 4);
    int fi    = gid % (F / 4);
    if (point >= BN) return;
    int idx = cell_of(coords, point, N);
    const float4 v = *(const float4*)(feat + (size_t)point * F + fi * 4);
    unsigned int* o = out + (size_t)idx * F + fi * 4;
    atomicMax(o + 0, enc_f32(v.x));
    atomicMax(o + 1, enc_f32(v.y));
    atomicMax(o + 2, enc_f32(v.z));
    atomicMax(o + 3, enc_f32(v.w));
}

__global__ void voxel_decode(unsigned int* __restrict__ out, int n4) {
    int i = blockIdx.x * blockDim.x + threadIdx.x;
    if (i >= n4) return;
    uint4 u = ((const uint4*)out)[i];
    float4 f;
    f.x = dec_f32(u.x); f.y = dec_f32(u.y);
    f.z = dec_f32(u.z); f.w = dec_f32(u.w);
    ((float4*)out)[i] = f;
}

// ---------- launch ----------

extern "C" void kernel_launch(void* const* d_in, const int* in_sizes, int n_in,
                              void* d_out, int out_size, void* d_ws, size_t ws_size,
                              hipStream_t stream) {
    const float* feat   = (const float*)d_in[0];
    const float* coords = (const float*)d_in[1];
    float* out          = (float*)d_out;

    const int BN = in_sizes[1] / 2;             // 131072 points
    const int F  = in_sizes[0] / BN;            // 256
    const int B  = out_size / (NCELL * F);      // 16
    const int N  = BN / B;                      // 8192
    const int totc = B * NCELL;                 // 16384

    // ws layout (uint): counts[totc] | ovf_cnt[16] | ovf_list[OVF_MAX] | sorted[totc*CAP]
    const size_t ws_need = ((size_t)totc + 16 + OVF_MAX + (size_t)totc * CAP) * 4;
    const bool fast_ok = (F == 256) && (B * N == BN) && (B * NCELL * F == out_size) &&
                         (ws_size >= ws_need);

    if (fast_ok) {
        unsigned int* counts   = (unsigned int*)d_ws;
        unsigned int* ovf_cnt  = counts + totc;
        unsigned int* ovf_list = ovf_cnt + 16;
        unsigned int* sorted   = ovf_list + OVF_MAX;

        zero_kernel<<<(totc + 16 + 255) / 256, 256, 0, stream>>>(counts, totc + 16);
        scatter_bucket<<<(BN + 255) / 256, 256, 0, stream>>>(coords, counts, sorted,
                                                             ovf_cnt, ovf_list, BN, N);
        gather_kernel<<<totc / 4, 256, 0, stream>>>(feat, coords, sorted, counts,
                                                    ovf_cnt, ovf_list, out, N, F);
    } else {
        hipMemsetAsync(d_out, 0, (size_t)out_size * sizeof(float), stream);
        int threads = BN * (F / 4);
        voxel_scatter_max<<<(threads + 255) / 256, 256, 0, stream>>>(feat, coords,
                                                                     (unsigned int*)d_out,
                                                                     BN, N, F);
        int n4 = out_size / 4;
        voxel_decode<<<(n4 + 255) / 256, 256, 0, stream>>>((unsigned int*)d_out, n4);
    }
}

// Round 7
// 39.512 us; speedup vs baseline: 6.3359x; 1.0005x over previous
//
#include <hip/hip_runtime.h>
#include <math.h>

#define VOXEL 32
#define NCELL (VOXEL * VOXEL)  // 1024 cells per batch
#define CAP 64                 // bucket capacity; Poisson(8) => P(>=64) ~ 1e-38
#define OVF_MAX 4096

// ---------- helpers ----------

__device__ __forceinline__ int cell_of(const float* __restrict__ coords, int point, int N) {
    float x = coords[(size_t)point * 2 + 0];
    float y = coords[(size_t)point * 2 + 1];
    int gx = (int)(x * (float)(VOXEL - 1));  // trunc == astype(int32) for x>=0
    int gy = (int)(y * (float)(VOXEL - 1));
    gx = min(max(gx, 0), VOXEL - 1);
    gy = min(max(gy, 0), VOXEL - 1);
    int b = point / N;
    return b * NCELL + gy * VOXEL + gx;
}

__device__ __forceinline__ void fmax2(float2& m, const float2 v) {
    m.x = fmaxf(m.x, v.x); m.y = fmaxf(m.y, v.y);
}

// ---------- 3-dispatch binned path ----------

__global__ void scatter_bucket(const float* __restrict__ coords,
                               unsigned int* __restrict__ counts,
                               unsigned int* __restrict__ sorted,
                               unsigned int* __restrict__ ovf_cnt,
                               unsigned int* __restrict__ ovf_list,
                               int BN, int N) {
    int p = blockIdx.x * blockDim.x + threadIdx.x;
    if (p >= BN) return;
    const float2 xy = ((const float2*)coords)[p];
    int gx = (int)(xy.x * (float)(VOXEL - 1));
    int gy = (int)(xy.y * (float)(VOXEL - 1));
    gx = min(max(gx, 0), VOXEL - 1);
    gy = min(max(gy, 0), VOXEL - 1);
    int c = (p / N) * NCELL + gy * VOXEL + gx;
    unsigned int pos = atomicAdd(&counts[c], 1u);
    if (pos < CAP) {
        sorted[(size_t)c * CAP + pos] = (unsigned int)p;
    } else {
        unsigned int o = atomicAdd(ovf_cnt, 1u);
        if (o < OVF_MAX) ovf_list[o] = (unsigned int)p;
    }
}

// Two waves per cell (feature-split): wave half h owns features
// [h*F/2 + lane*2, +2). 64 lanes x 8B = 512B contiguous per row segment.
// 8-wide batches with clamped index: 8 independent loads in flight; padded
// slots re-read the last row (L1 hit). Overflow folded in (cold path).
__global__ void __launch_bounds__(256)
gather_kernel(const float* __restrict__ feat,
              const float* __restrict__ coords,
              const unsigned int* __restrict__ sorted,
              const unsigned int* __restrict__ counts,
              const unsigned int* __restrict__ ovf_cnt,
              const unsigned int* __restrict__ ovf_list,
              float* __restrict__ out, int N, int F) {
    const int wave = threadIdx.x >> 6;          // 0..3
    const int lane = threadIdx.x & 63;
    const int gw   = blockIdx.x * 4 + wave;     // global wave id
    const int cell = gw >> 1;
    const int half = gw & 1;
    const int foff = half * (F / 2) + lane * 2; // this wave-lane's feature offset

    const unsigned int raw = counts[cell];
    const int cnt = (int)min(raw, (unsigned int)CAP);
    const size_t cb = (size_t)cell * CAP;
    unsigned int pid_l = (lane < cnt) ? sorted[cb + lane] : 0u;

    float2 m = make_float2(-INFINITY, -INFINITY);
    const int e = cnt - 1;
    for (int j = 0; j < cnt; j += 8) {
        const int p0 = __shfl((int)pid_l, min(j + 0, e));
        const int p1 = __shfl((int)pid_l, min(j + 1, e));
        const int p2 = __shfl((int)pid_l, min(j + 2, e));
        const int p3 = __shfl((int)pid_l, min(j + 3, e));
        const int p4 = __shfl((int)pid_l, min(j + 4, e));
        const int p5 = __shfl((int)pid_l, min(j + 5, e));
        const int p6 = __shfl((int)pid_l, min(j + 6, e));
        const int p7 = __shfl((int)pid_l, min(j + 7, e));
        const float2 v0 = *(const float2*)(feat + (size_t)p0 * F + foff);
        const float2 v1 = *(const float2*)(feat + (size_t)p1 * F + foff);
        const float2 v2 = *(const float2*)(feat + (size_t)p2 * F + foff);
        const float2 v3 = *(const float2*)(feat + (size_t)p3 * F + foff);
        const float2 v4 = *(const float2*)(feat + (size_t)p4 * F + foff);
        const float2 v5 = *(const float2*)(feat + (size_t)p5 * F + foff);
        const float2 v6 = *(const float2*)(feat + (size_t)p6 * F + foff);
        const float2 v7 = *(const float2*)(feat + (size_t)p7 * F + foff);
        fmax2(m, v0); fmax2(m, v1); fmax2(m, v2); fmax2(m, v3);
        fmax2(m, v4); fmax2(m, v5); fmax2(m, v6); fmax2(m, v7);
    }

    // Cold path: points that spilled past CAP anywhere in the grid.
    const unsigned int novf = *ovf_cnt;
    if (novf != 0u) {
        const int n = (int)min(novf, (unsigned int)OVF_MAX);
        for (int i = 0; i < n; ++i) {
            const unsigned int p = ovf_list[i];
            if (cell_of(coords, (int)p, N) == cell) {
                const float2 v = *(const float2*)(feat + (size_t)p * F + foff);
                fmax2(m, v);
            }
        }
    }

    if (raw == 0u) m = make_float2(0.f, 0.f);
    *(float2*)(out + (size_t)cell * F + foff) = m;
}

// ---------- last-resort fallback (round-1 atomic path, any F%4==0) ----------

__device__ __forceinline__ unsigned int enc_f32(float f) {
    unsigned int u = __float_as_uint(f);
    return (u & 0x80000000u) ? ~u : (u | 0x80000000u);
}
__device__ __forceinline__ float dec_f32(unsigned int u) {
    if (u == 0u) return 0.0f;
    return __uint_as_float((u & 0x80000000u) ? (u ^ 0x80000000u) : ~u);
}

__global__ void voxel_scatter_max(const float* __restrict__ feat,
                                  const float* __restrict__ coords,
                                  unsigned int* __restrict__ out,
                                  int BN, int N, int F) {
    int gid   = blockIdx.x * blockDim.x + threadIdx.x;
    int point = gid / (F / 4);
    int fi    = gid % (F / 4);
    if (point >= BN) return;
    int idx = cell_of(coords, point, N);
    const float4 v = *(const float4*)(feat + (size_t)point * F + fi * 4);
    unsigned int* o = out + (size_t)idx * F + fi * 4;
    atomicMax(o + 0, enc_f32(v.x));
    atomicMax(o + 1, enc_f32(v.y));
    atomicMax(o + 2, enc_f32(v.z));
    atomicMax(o + 3, enc_f32(v.w));
}

__global__ void voxel_decode(unsigned int* __restrict__ out, int n4) {
    int i = blockIdx.x * blockDim.x + threadIdx.x;
    if (i >= n4) return;
    uint4 u = ((const uint4*)out)[i];
    float4 f;
    f.x = dec_f32(u.x); f.y = dec_f32(u.y);
    f.z = dec_f32(u.z); f.w = dec_f32(u.w);
    ((float4*)out)[i] = f;
}

// ---------- launch ----------

extern "C" void kernel_launch(void* const* d_in, const int* in_sizes, int n_in,
                              void* d_out, int out_size, void* d_ws, size_t ws_size,
                              hipStream_t stream) {
    const float* feat   = (const float*)d_in[0];
    const float* coords = (const float*)d_in[1];
    float* out          = (float*)d_out;

    const int BN = in_sizes[1] / 2;             // 131072 points
    const int F  = in_sizes[0] / BN;            // 256
    const int B  = out_size / (NCELL * F);      // 16
    const int N  = BN / B;                      // 8192
    const int totc = B * NCELL;                 // 16384

    // ws layout (uint): counts[totc] | ovf_cnt[16] | ovf_list[OVF_MAX] | sorted[totc*CAP]
    const size_t ws_need = ((size_t)totc + 16 + OVF_MAX + (size_t)totc * CAP) * 4;
    const bool fast_ok = (F == 256) && (B * N == BN) && (B * NCELL * F == out_size) &&
                         (ws_size >= ws_need);

    if (fast_ok) {
        unsigned int* counts   = (unsigned int*)d_ws;
        unsigned int* ovf_cnt  = counts + totc;
        unsigned int* ovf_list = ovf_cnt + 16;
        unsigned int* sorted   = ovf_list + OVF_MAX;

        // zero counts + ovf_cnt (contiguous) via runtime fill
        hipMemsetAsync(counts, 0, (size_t)(totc + 16) * sizeof(unsigned int), stream);
        scatter_bucket<<<(BN + 255) / 256, 256, 0, stream>>>(coords, counts, sorted,
                                                             ovf_cnt, ovf_list, BN, N);
        // 2 waves per cell -> totc*2 waves, 4 waves per 256-thread block
        gather_kernel<<<totc * 2 / 4, 256, 0, stream>>>(feat, coords, sorted, counts,
                                                        ovf_cnt, ovf_list, out, N, F);
    } else {
        hipMemsetAsync(d_out, 0, (size_t)out_size * sizeof(float), stream);
        int threads = BN * (F / 4);
        voxel_scatter_max<<<(threads + 255) / 256, 256, 0, stream>>>(feat, coords,
                                                                     (unsigned int*)d_out,
                                                                     BN, N, F);
        int n4 = out_size / 4;
        voxel_decode<<<(n4 + 255) / 256, 256, 0, stream>>>((unsigned int*)d_out, n4);
    }
}